// Round 3
// baseline (392.623 us; speedup 1.0000x reference)
//
#include <hip/hip_runtime.h>

#define T_LEN 16384
#define N_TOT 131072          // 8 * 16384
#define ROWS 64               // timesteps per block
#define XROWS 68              // ROWS + DIL(4) history rows
#define XPITCH 136            // 128 + 8 pad (stride % 32 dwords == 4 -> 2-way, free)
#define MPITCH 264            // 256 + 8 pad

typedef __attribute__((ext_vector_type(8))) short short8;
typedef __attribute__((ext_vector_type(4))) short short4v;
typedef __attribute__((ext_vector_type(4))) float floatx4;
typedef unsigned short ushort_t;

__device__ __forceinline__ ushort_t f2bf(float f) {
    unsigned int u = __float_as_uint(f);
    u += 0x7fffu + ((u >> 16) & 1u);        // RNE
    return (ushort_t)(u >> 16);
}

// Repack fp32 weights into bf16 [kc][n][kk32] so each lane's MFMA B-fragment
// (B[k=quad*8+j][n=l16]) is one contiguous 16B load.
// W1: K=256 (k<128: tap1 = x[t]; k>=128: tap0 = x[t-4]), N=512 (tanh | sig)
// W2: K=256 (merged ch), N=384 (res 128 | skip 256)
__global__ void repack_w(const float* __restrict__ w_tanh,
                         const float* __restrict__ w_sig,
                         const float* __restrict__ w_res,
                         const float* __restrict__ w_skip,
                         ushort_t* __restrict__ w1,
                         ushort_t* __restrict__ w2) {
    int i = blockIdx.x * 256 + threadIdx.x;
    if (i < 8 * 512 * 32) {
        int kk = i & 31;
        int n  = (i >> 5) & 511;
        int kc = i >> 14;
        int k  = kc * 32 + kk;
        int tap = (k < 128) ? 1 : 0;
        int cin = k & 127;
        float v = (n < 256) ? w_tanh[(tap * 128 + cin) * 256 + n]
                            : w_sig [(tap * 128 + cin) * 256 + (n - 256)];
        w1[i] = f2bf(v);
    } else {
        int j = i - 8 * 512 * 32;
        if (j < 8 * 384 * 32) {
            int kk = j & 31;
            int n  = (j >> 5) % 384;
            int kc = j / (384 * 32);
            int k  = kc * 32 + kk;
            float v = (n < 128) ? w_res[k * 128 + n]
                                : w_skip[k * 256 + (n - 128)];
            w2[j] = f2bf(v);
        }
    }
}

__global__ __launch_bounds__(512)
void fused_block(const float* __restrict__ x,
                 const float* __restrict__ b_tanh,
                 const float* __restrict__ b_sig,
                 const float* __restrict__ b_res,
                 const float* __restrict__ b_skip,
                 const ushort_t* __restrict__ w1,
                 const ushort_t* __restrict__ w2,
                 float* __restrict__ out) {
    __shared__ ushort_t xbuf[XROWS * XPITCH];
    __shared__ ushort_t mbuf[ROWS * MPITCH];

    const int tid = threadIdx.x;
    const int n0  = blockIdx.x * ROWS;        // flat row base (b*T + t0)
    const int t0  = n0 & (T_LEN - 1);         // within-batch t (64 | 16384)

    // ---- stage X rows [t0-4, t0+64) into LDS, fp32 -> bf16 ----
    for (int idx = tid; idx < XROWS * 32; idx += 512) {
        int r  = idx >> 5;
        int c4 = (idx & 31) << 2;
        int t  = t0 - 4 + r;
        short4v s;
        if (t >= 0) {
            floatx4 v = *(const floatx4*)(x + (size_t)(n0 - 4 + r) * 128 + c4);
            s = short4v{(short)f2bf(v[0]), (short)f2bf(v[1]),
                        (short)f2bf(v[2]), (short)f2bf(v[3])};
        } else {
            s = short4v{0, 0, 0, 0};
        }
        *(short4v*)(xbuf + r * XPITCH + c4) = s;
    }
    __syncthreads();

    const int w    = tid >> 6;
    const int lane = tid & 63;
    const int quad = lane >> 4;
    const int l16  = lane & 15;

    const floatx4 zero4 = {0.f, 0.f, 0.f, 0.f};

    // ---- GEMM1: [64 x 256] x [256 x 512]; wave w owns tanh/sig cols [32w, 32w+32) ----
    floatx4 acc_t[4][2], acc_s[4][2];
    #pragma unroll
    for (int rt = 0; rt < 4; ++rt)
        #pragma unroll
        for (int ct = 0; ct < 2; ++ct) { acc_t[rt][ct] = zero4; acc_s[rt][ct] = zero4; }

    #pragma unroll
    for (int kc = 0; kc < 8; ++kc) {
        const int colb = (kc & 3) * 32 + quad * 8;
        const int roff = (kc < 4) ? 4 : 0;    // kc<4: x[t] (buffer row r+4); else x[t-4]
        short8 a[4];
        #pragma unroll
        for (int rt = 0; rt < 4; ++rt)
            a[rt] = *(const short8*)(xbuf + (rt * 16 + l16 + roff) * XPITCH + colb);
        short8 bt[2], bs[2];
        #pragma unroll
        for (int ct = 0; ct < 2; ++ct) {
            int n_t = 32 * w + ct * 16 + l16;
            bt[ct] = *(const short8*)(w1 + ((kc * 512 + n_t)       * 32) + quad * 8);
            bs[ct] = *(const short8*)(w1 + ((kc * 512 + n_t + 256) * 32) + quad * 8);
        }
        #pragma unroll
        for (int rt = 0; rt < 4; ++rt)
            #pragma unroll
            for (int ct = 0; ct < 2; ++ct) {
                acc_t[rt][ct] = __builtin_amdgcn_mfma_f32_16x16x32_bf16(a[rt], bt[ct], acc_t[rt][ct], 0, 0, 0);
                acc_s[rt][ct] = __builtin_amdgcn_mfma_f32_16x16x32_bf16(a[rt], bs[ct], acc_s[rt][ct], 0, 0, 0);
            }
    }

    // ---- gate: merged = tanh(pt) * sigmoid(ps), write bf16 to LDS ----
    #pragma unroll
    for (int ct = 0; ct < 2; ++ct) {
        int c = 32 * w + ct * 16 + l16;
        float btb = b_tanh[c];
        float bsb = b_sig[c];
        #pragma unroll
        for (int rt = 0; rt < 4; ++rt)
            #pragma unroll
            for (int i = 0; i < 4; ++i) {
                float pt = acc_t[rt][ct][i] + btb;
                float ps = acc_s[rt][ct][i] + bsb;
                float e2 = __expf(2.0f * pt);
                float th = 1.0f - 2.0f / (e2 + 1.0f);     // stable tanh
                float sg = 1.0f / (1.0f + __expf(-ps));
                int row = rt * 16 + quad * 4 + i;          // C/D: col=l16, row=quad*4+reg
                mbuf[row * MPITCH + c] = f2bf(th * sg);
            }
    }
    __syncthreads();

    // ---- GEMM2: [64 x 256] x [256 x 384]; wave w owns cols [48w, 48w+48) ----
    floatx4 acc2[4][3];
    #pragma unroll
    for (int rt = 0; rt < 4; ++rt)
        #pragma unroll
        for (int ct = 0; ct < 3; ++ct) acc2[rt][ct] = zero4;

    #pragma unroll
    for (int kc = 0; kc < 8; ++kc) {
        short8 a[4];
        #pragma unroll
        for (int rt = 0; rt < 4; ++rt)
            a[rt] = *(const short8*)(mbuf + (rt * 16 + l16) * MPITCH + kc * 32 + quad * 8);
        short8 b[3];
        #pragma unroll
        for (int ct = 0; ct < 3; ++ct) {
            int n2 = 48 * w + ct * 16 + l16;
            b[ct] = *(const short8*)(w2 + (kc * 384 + n2) * 32 + quad * 8);
        }
        #pragma unroll
        for (int rt = 0; rt < 4; ++rt)
            #pragma unroll
            for (int ct = 0; ct < 3; ++ct)
                acc2[rt][ct] = __builtin_amdgcn_mfma_f32_16x16x32_bf16(a[rt], b[ct], acc2[rt][ct], 0, 0, 0);
    }

    // ---- epilogue (fp32 out): res cols [0,128): +b_res + x; skip cols [128,384): +b_skip ----
    #pragma unroll
    for (int ct = 0; ct < 3; ++ct) {
        int col = 48 * w + ct * 16 + l16;
        if (col < 128) {
            float bb = b_res[col];
            #pragma unroll
            for (int rt = 0; rt < 4; ++rt)
                #pragma unroll
                for (int i = 0; i < 4; ++i) {
                    int row = rt * 16 + quad * 4 + i;
                    size_t g = (size_t)(n0 + row);
                    out[g * 128 + col] = acc2[rt][ct][i] + bb + x[g * 128 + col];
                }
        } else {
            int c2 = col - 128;
            float bb = b_skip[c2];
            #pragma unroll
            for (int rt = 0; rt < 4; ++rt)
                #pragma unroll
                for (int i = 0; i < 4; ++i) {
                    int row = rt * 16 + quad * 4 + i;
                    size_t g = (size_t)(n0 + row);
                    out[(size_t)N_TOT * 128 + g * 256 + c2] = acc2[rt][ct][i] + bb;
                }
        }
    }
}

extern "C" void kernel_launch(void* const* d_in, const int* in_sizes, int n_in,
                              void* d_out, int out_size, void* d_ws, size_t ws_size,
                              hipStream_t stream) {
    const float* x      = (const float*)d_in[0];
    const float* w_tanh = (const float*)d_in[1];
    const float* b_tanh = (const float*)d_in[2];
    const float* w_sig  = (const float*)d_in[3];
    const float* b_sig  = (const float*)d_in[4];
    const float* w_res  = (const float*)d_in[5];
    const float* b_res  = (const float*)d_in[6];
    const float* w_skip = (const float*)d_in[7];
    const float* b_skip = (const float*)d_in[8];

    ushort_t* w1 = (ushort_t*)d_ws;            // 8*512*32 = 131072 bf16 (256 KB)
    ushort_t* w2 = w1 + 8 * 512 * 32;          // 8*384*32 =  98304 bf16 (192 KB)
    float* out = (float*)d_out;

    // 131072 + 98304 = 229376 threads
    repack_w<<<896, 256, 0, stream>>>(w_tanh, w_sig, w_res, w_skip, w1, w2);
    fused_block<<<N_TOT / ROWS, 512, 0, stream>>>(x, b_tanh, b_sig, b_res, b_skip, w1, w2, out);
}